// Round 4
// baseline (538.012 us; speedup 1.0000x reference)
//
#include <hip/hip_runtime.h>
#include <hip/hip_bf16.h>

typedef unsigned short u16;
typedef unsigned int u32;
typedef __bf16 bf16x8 __attribute__((ext_vector_type(8)));
typedef float f32x4 __attribute__((ext_vector_type(4)));

#define CH 128
#define NB 32
#define SCALE_F 0.17677669529663687f

__device__ __forceinline__ u16 b2u(__bf16 h) {
  union { __bf16 h; u16 u; } v; v.h = h; return v.u;
}
__device__ __forceinline__ u16 f2b(float f) { return b2u((__bf16)f); }
__device__ __forceinline__ u32 pk2(float lo, float hi) {
  union { __bf16 h[2]; u32 w; } v; v.h[0] = (__bf16)lo; v.h[1] = (__bf16)hi; return v.w;
}

// ---------------------------------------------------------------- prep ----
__global__ void prep_kernel(const float* __restrict__ qw, const float* __restrict__ ow,
                            u16* __restrict__ wq, u16* __restrict__ wo,
                            float* __restrict__ stats) {
  int t = blockIdx.x * 256 + threadIdx.x;           // 192 blocks
  if (t < 49152) wq[t] = f2b(qw[t]);
  if (t < 16384) wo[t] = f2b(ow[t]);
  if (t < 8192)  stats[t] = 0.0f;
}

// ------------------------------------------------------------ main pass ---
// 1 block = 1 sample, 4 waves, wave w owns head w. Two barriers. LDS 26624 B.
__global__ __launch_bounds__(256, 6) void attn_kernel(
    const float* __restrict__ x, const u16* __restrict__ wq,
    const float* __restrict__ qkv_b, const u16* __restrict__ wo,
    const float* __restrict__ out_b, const float* __restrict__ rel,
    float* __restrict__ out, float* __restrict__ stats,
    u16* __restrict__ preb) {

  // pool: [0,8192)   per-wave q/k (32x64, XOR-swz), later aliased by P (stride 40)
  //                  and after barrier #1 by sO (32x136)
  //       [8192,13312) per-wave V (32x40)
  __shared__ __attribute__((aligned(16))) u16 pool[13312];

  const int tid = threadIdx.x;
  const int w = tid >> 6, lane = tid & 63;
  const int g = lane >> 4, l15 = lane & 15;
  const int b = blockIdx.x, h = w;
  const float* xb = x + (size_t)b * (CH * NB);
  const f32x4 zf = {0.f, 0.f, 0.f, 0.f};

  u16* sQKw = pool + w * 2048;          // [n][o'] o'<32: q(scaled), o'>=32: k; XOR swz
  u16* sVw  = pool + 8192 + w * 1280;   // [d][m] stride 40
  u16* sPw  = sQKw;                      // P [q][k] stride 40 (aliases q/k after 2b)
  u16* sO   = pool;                      // O^T [n][c] stride 136 (after barrier #1)

  // lane-resident rel-pos table: lane L holds rel[L][h]
  const float relv = rel[(lane < 63 ? lane : 62) * 4 + h];

  // ---- phase 1: QKV rows of head h: 6 row-tiles (q,k,v x 2 d-tiles)
  f32x4 acc[6][2];
  #pragma unroll
  for (int tt = 0; tt < 6; ++tt)
    #pragma unroll
    for (int ct = 0; ct < 2; ++ct) acc[tt][ct] = zf;

  #pragma unroll
  for (int kk = 0; kk < 4; ++kk) {
    bf16x8 bfr[2];
    #pragma unroll
    for (int ct = 0; ct < 2; ++ct) {
      #pragma unroll
      for (int j = 0; j < 8; ++j)
        bfr[ct][j] = (__bf16)xb[(kk * 32 + 8 * g + j) * NB + 16 * ct + l15];
    }
    #pragma unroll
    for (int tt = 0; tt < 6; ++tt) {
      const int part = tt >> 1, td = tt & 1;         // part 0=q 1=k 2=v
      const int row = part * 128 + h * 32 + 16 * td + l15;
      bf16x8 afr = *(const bf16x8*)&wq[row * 128 + kk * 32 + 8 * g];
      acc[tt][0] = __builtin_amdgcn_mfma_f32_16x16x32_bf16(afr, bfr[0], acc[tt][0], 0, 0, 0);
      acc[tt][1] = __builtin_amdgcn_mfma_f32_16x16x32_bf16(afr, bfr[1], acc[tt][1], 0, 0, 0);
    }
  }

  // ---- phase 2a: +bias; q(pre-scaled),k -> sQKw (transposed, swz, b32 pairs);
  //                v -> sVw [d][m]
  #pragma unroll
  for (int tt = 0; tt < 4; ++tt) {                   // q,k only
    const int part = tt >> 1, td = tt & 1;
    #pragma unroll
    for (int rp = 0; rp < 4; rp += 2) {
      const int d0 = 16 * td + 4 * g + rp;
      float b0 = qkv_b[part * 128 + h * 32 + d0];
      float b1 = qkv_b[part * 128 + h * 32 + d0 + 1];
      #pragma unroll
      for (int ct = 0; ct < 2; ++ct) {
        const int n = 16 * ct + l15;
        float v0 = acc[tt][ct][rp]     + b0;
        float v1 = acc[tt][ct][rp + 1] + b1;
        if (part == 0) { v0 *= SCALE_F; v1 *= SCALE_F; }
        const int idx = (n * 64 + part * 32 + d0) ^ ((n & 7) << 3);
        *(u32*)&sQKw[idx] = pk2(v0, v1);
      }
    }
  }
  #pragma unroll
  for (int td = 0; td < 2; ++td) {                   // v
    #pragma unroll
    for (int r = 0; r < 4; ++r) {
      const int d = 16 * td + 4 * g + r;
      const float bv = qkv_b[256 + h * 32 + d];
      #pragma unroll
      for (int ct = 0; ct < 2; ++ct) {
        const int n = 16 * ct + l15;
        sVw[d * 40 + n] = f2b(acc[4 + td][ct][r] + bv);
      }
    }
  }

  // ---- phase 2b: S^T = K @ Q^T -> C col=query(l15), rows=key(4g+r)
  bf16x8 qf[2], kf[2];
  #pragma unroll
  for (int t2 = 0; t2 < 2; ++t2) {
    const int n = 16 * t2 + l15;
    qf[t2] = *(const bf16x8*)&sQKw[(n * 64 + 8 * g)      ^ ((n & 7) << 3)];
    kf[t2] = *(const bf16x8*)&sQKw[(n * 64 + 32 + 8 * g) ^ ((n & 7) << 3)];
  }
  f32x4 st[2][2];   // [tm: key-tile][tn: query-tile]
  #pragma unroll
  for (int tm = 0; tm < 2; ++tm)
    #pragma unroll
    for (int tn = 0; tn < 2; ++tn)
      st[tm][tn] = __builtin_amdgcn_mfma_f32_16x16x32_bf16(kf[tm], qf[tn], zf, 0, 0, 0);

  // ---- phase 2c: softmax over keys: 8 lane-local + xor16 + xor32; P^T->LDS
  #pragma unroll
  for (int tn = 0; tn < 2; ++tn) {
    float v[2][4];
    #pragma unroll
    for (int tm = 0; tm < 2; ++tm)
      #pragma unroll
      for (int r = 0; r < 4; ++r) {
        const int idx = (16 * tm + 4 * g + r) - (16 * tn + l15) + 31;  // 0..62
        v[tm][r] = st[tm][tn][r] + __shfl(relv, idx);
      }
    float mx = fmaxf(fmaxf(fmaxf(v[0][0], v[0][1]), fmaxf(v[0][2], v[0][3])),
                     fmaxf(fmaxf(v[1][0], v[1][1]), fmaxf(v[1][2], v[1][3])));
    mx = fmaxf(mx, __shfl_xor(mx, 16));
    mx = fmaxf(mx, __shfl_xor(mx, 32));
    float e[2][4], sm = 0.f;
    #pragma unroll
    for (int tm = 0; tm < 2; ++tm)
      #pragma unroll
      for (int r = 0; r < 4; ++r) { e[tm][r] = __expf(v[tm][r] - mx); sm += e[tm][r]; }
    sm += __shfl_xor(sm, 16);
    sm += __shfl_xor(sm, 32);
    const float ri = 1.0f / sm;
    #pragma unroll
    for (int tm = 0; tm < 2; ++tm)
      #pragma unroll
      for (int rp = 0; rp < 4; rp += 2) {
        const int q = 16 * tn + l15;
        *(u32*)&sPw[q * 40 + 16 * tm + 4 * g + rp] =
            pk2(e[tm][rp] * ri, e[tm][rp + 1] * ri);
      }
  }

  // ---- phase 2d: O = P @ V -> C col=d(l15), row=query(4g+r)
  bf16x8 pf[2], vf[2];
  #pragma unroll
  for (int t2 = 0; t2 < 2; ++t2) {
    pf[t2] = *(const bf16x8*)&sPw[(16 * t2 + l15) * 40 + 8 * g];
    vf[t2] = *(const bf16x8*)&sVw[(16 * t2 + l15) * 40 + 8 * g];
  }
  __syncthreads();   // #1: all waves' q/k/P reads drained before sO overwrites pool

  f32x4 oacc[2][2];   // [tn][td]
  #pragma unroll
  for (int tn = 0; tn < 2; ++tn)
    #pragma unroll
    for (int td = 0; td < 2; ++td)
      oacc[tn][td] = __builtin_amdgcn_mfma_f32_16x16x32_bf16(pf[tn], vf[td], zf, 0, 0, 0);

  #pragma unroll
  for (int tn = 0; tn < 2; ++tn)
    #pragma unroll
    for (int td = 0; td < 2; ++td)
      #pragma unroll
      for (int r = 0; r < 4; ++r) {
        const int n = 16 * tn + 4 * g + r;
        const int c = h * 32 + 16 * td + l15;
        sO[n * 136 + c] = f2b(oacc[tn][td][r]);
      }

  __syncthreads();   // #2: sO complete before cross-wave out-proj

  // ---- phase 3: out-proj rows 32w..32w+31 + residual + stats
  f32x4 pacc[2][2];
  #pragma unroll
  for (int mi = 0; mi < 2; ++mi)
    #pragma unroll
    for (int ct = 0; ct < 2; ++ct) pacc[mi][ct] = zf;

  #pragma unroll
  for (int kk = 0; kk < 4; ++kk) {
    bf16x8 bfr[2];
    #pragma unroll
    for (int ct = 0; ct < 2; ++ct)
      bfr[ct] = *(const bf16x8*)&sO[(16 * ct + l15) * 136 + kk * 32 + 8 * g];
    #pragma unroll
    for (int mi = 0; mi < 2; ++mi) {
      const int row = 32 * w + 16 * mi + l15;
      bf16x8 afr = *(const bf16x8*)&wo[row * 128 + kk * 32 + 8 * g];
      pacc[mi][0] = __builtin_amdgcn_mfma_f32_16x16x32_bf16(afr, bfr[0], pacc[mi][0], 0, 0, 0);
      pacc[mi][1] = __builtin_amdgcn_mfma_f32_16x16x32_bf16(afr, bfr[1], pacc[mi][1], 0, 0, 0);
    }
  }

  float* ob = out + (size_t)b * (CH * NB);
  u16* pb = preb ? preb + (size_t)b * (CH * NB) : (u16*)0;
  #pragma unroll
  for (int mi = 0; mi < 2; ++mi) {
    #pragma unroll
    for (int r = 0; r < 4; ++r) {
      const int o = 32 * w + 16 * mi + 4 * g + r;
      const float bias = out_b[o];
      float ssum = 0.f, ssq = 0.f;
      #pragma unroll
      for (int ct = 0; ct < 2; ++ct) {
        const int n = 16 * ct + l15;
        const float val = pacc[mi][ct][r] + bias + xb[o * NB + n];
        if (pb) pb[o * NB + n] = f2b(val);
        else    ob[o * NB + n] = val;
        ssum += val; ssq += val * val;
      }
      #pragma unroll
      for (int msk = 1; msk < 16; msk <<= 1) {
        ssum += __shfl_xor(ssum, msk);
        ssq  += __shfl_xor(ssq, msk);
      }
      if (l15 == 0) {
        atomicAdd(&stats[(b & 31) * 128 + o], ssum);
        atomicAdd(&stats[4096 + (b & 31) * 128 + o], ssq);
      }
    }
  }
}

// ------------------------------------------------------------- BN stats ---
__global__ void bnstats_kernel(const float* __restrict__ stats,
                               const float* __restrict__ gamma,
                               const float* __restrict__ beta,
                               float* __restrict__ sc, float* __restrict__ sh,
                               float invM) {
  int c = threadIdx.x;
  if (c >= 128) return;
  float s = 0.f, q = 0.f;
  #pragma unroll 8
  for (int i = 0; i < 32; ++i) {
    s += stats[i * 128 + c];
    q += stats[4096 + i * 128 + c];
  }
  float mean = s * invM;
  float var  = q * invM - mean * mean;
  float rstd = rsqrtf(var + 1e-5f);
  float a = gamma[c] * rstd;
  sc[c] = a;
  sh[c] = beta[c] - mean * a;
}

// ------------------------------------------------------- BN apply (f32) ---
__global__ __launch_bounds__(256) void bnapply_kernel(float* __restrict__ out,
                                                      const float* __restrict__ sc,
                                                      const float* __restrict__ sh,
                                                      int n4total) {
  int i = blockIdx.x * 256 + threadIdx.x;
  int stride = gridDim.x * 256;
  for (; i < n4total; i += stride) {
    int c = (i >> 3) & 127;
    float a = sc[c], d = sh[c];
    float4 v = ((float4*)out)[i];
    v.x = v.x * a + d;
    v.y = v.y * a + d;
    v.z = v.z * a + d;
    v.w = v.w * a + d;
    ((float4*)out)[i] = v;
  }
}

// ------------------------------------------------------ BN apply (bf16) ---
__global__ __launch_bounds__(256) void bnapply_bf16_kernel(
    const u16* __restrict__ preb, float* __restrict__ out,
    const float* __restrict__ sc, const float* __restrict__ sh, int n4total) {
  int i = blockIdx.x * 256 + threadIdx.x;
  int stride = gridDim.x * 256;
  for (; i < n4total; i += stride) {
    int c = (i >> 3) & 127;
    float a = sc[c], d = sh[c];
    uint2 u = ((const uint2*)preb)[i];
    float4 v;
    union { u32 w; float f; } t;
    t.w = (u.x & 0xffffu) << 16; v.x = t.f * a + d;
    t.w = (u.x & 0xffff0000u);   v.y = t.f * a + d;
    t.w = (u.y & 0xffffu) << 16; v.z = t.f * a + d;
    t.w = (u.y & 0xffff0000u);   v.w = t.f * a + d;
    ((float4*)out)[i] = v;
  }
}

// --------------------------------------------------------------- launch ---
extern "C" void kernel_launch(void* const* d_in, const int* in_sizes, int n_in,
                              void* d_out, int out_size, void* d_ws, size_t ws_size,
                              hipStream_t stream) {
  const float* x     = (const float*)d_in[0];
  const float* qkv_w = (const float*)d_in[1];
  const float* qkv_b = (const float*)d_in[2];
  const float* out_w = (const float*)d_in[3];
  const float* out_b = (const float*)d_in[4];
  const float* rel   = (const float*)d_in[5];
  const float* gamma = (const float*)d_in[6];
  const float* beta  = (const float*)d_in[7];
  float* out = (float*)d_out;

  const int B = in_sizes[0] / (CH * NB);      // 8192

  u16* wq = (u16*)d_ws;                       // [384*128] bf16
  u16* wo = wq + 49152;                       // [128*128] bf16
  float* stats = (float*)(wo + 16384);        // 32 slots x 128 sum + sumsq
  float* sc = stats + 8192;
  float* sh = sc + 128;
  u16* preb = (u16*)(sh + 128);               // optional bf16 pre-BN staging

  const size_t need = (size_t)(49152 + 16384) * 2 + (size_t)8448 * 4
                    + (size_t)B * CH * NB * 2;
  const bool useB16 = ws_size >= need;

  prep_kernel<<<192, 256, 0, stream>>>(qkv_w, out_w, wq, wo, stats);
  attn_kernel<<<B, 256, 0, stream>>>(x, wq, qkv_b, wo, out_b, rel, out, stats,
                                     useB16 ? preb : (u16*)0);
  bnstats_kernel<<<1, 128, 0, stream>>>(stats, gamma, beta, sc, sh, 1.0f / (float)(B * NB));
  if (useB16)
    bnapply_bf16_kernel<<<2048, 256, 0, stream>>>(preb, out, sc, sh, out_size / 4);
  else
    bnapply_kernel<<<2048, 256, 0, stream>>>(out, sc, sh, out_size / 4);
}